// Round 3
// baseline (1416418.945 us; speedup 1.0000x reference)
//
#include <hip/hip_runtime.h>
#include <cstdint>
#include <cstddef>

#define TT 65536
#define KK 512
#define NEGV (-10000.0f)
#define SEG 256
#define NSEG 256  // TT/SEG

typedef unsigned short u16;
typedef unsigned int   u32;
typedef unsigned long long u64;

__device__ __forceinline__ float u2f(u32 b){ union{u32 u; float f;} x; x.u=b; return x.f; }
__device__ __forceinline__ u32 f2u(float f){ union{u32 u; float f;} x; x.f=f; return x.u; }

// ---------------------------------------------------------------------------
// Per-row sort of transitions, desc by value, asc index on ties.
// svp[n*KK+k] = ((u64)p << 32) | float_bits(v)
// ---------------------------------------------------------------------------
__global__ __launch_bounds__(512)
void sort_rows(const float* __restrict__ trans, u64* __restrict__ svp)
{
    __shared__ u64 s[KK];
    const int n = blockIdx.x, i = threadIdx.x;
    float x = trans[n*KK + i];
    u32 b = f2u(x);
    u32 ord = (b & 0x80000000u) ? ~b : (b | 0x80000000u);   // monotone u32 order
    s[i] = ((u64)(~ord) << 16) | (u32)i;                    // asc sort => value desc, p asc
    __syncthreads();
    for (int k = 2; k <= KK; k <<= 1){
        for (int j = k >> 1; j > 0; j >>= 1){
            int ixj = i ^ j;
            if (ixj > i){
                u64 a = s[i], c = s[ixj];
                bool up = ((i & k) == 0);
                if ((a > c) == up){ s[i] = c; s[ixj] = a; }
            }
            __syncthreads();
        }
    }
    u64 key = s[i];
    u32 p    = (u32)(key & 0xFFFFu);
    u32 ordv = ~(u32)(key >> 16);
    u32 bits = (ordv & 0x80000000u) ? (ordv ^ 0x80000000u) : ~ordv;
    svp[(size_t)n*KK + i] = ((u64)p << 32) | bits;
}

// transT[p*KK + n] = trans[n*KK + p]  (gather trans[n,p] lane-coalesced in n)
__global__ __launch_bounds__(512)
void transpose_k(const float* __restrict__ t, float* __restrict__ tt)
{
    const int c = blockIdx.x, r = threadIdx.x;
    tt[(size_t)c*KK + r] = t[(size_t)r*KK + c];
}

// ---------------------------------------------------------------------------
// Main scan: 1 block, 512 threads. Thread i owns tag i.
// Threshold-algorithm pruning: fv-band masks (edges fvmax-{0.5,1,2,4}) walked
// in prefetched batches of 4, interleaved with v-sorted register candidates;
// termination bound fl(Bprev + cV[k]) checked after EVERY batch (exact via
// fp-add monotonicity; strict < so ties are never skipped; 3-way compare
// reproduces numpy first-index argmax).
// ---------------------------------------------------------------------------
__global__ __launch_bounds__(512, 2)
void viterbi_scan(const float* __restrict__ feats,
                  const u64* __restrict__ svp,
                  const float* __restrict__ transT,
                  u16* __restrict__ bp,
                  float* __restrict__ outScore, int* __restrict__ bestOut)
{
    __shared__ float fvb[2][KK];
    __shared__ float wmaxS[2][8];
    __shared__ u64  bmS[2][4][8];
    __shared__ float rv[KK];
    __shared__ int   ri[KK];

    const int i = threadIdx.x;
    const int lane = i & 63, wv = i >> 6;

    // top-32 (v,p) candidates for own row, v desc. p packed 2x16b per reg.
    float cV[32]; u32 cPp[16];
#pragma unroll
    for (int k = 0; k < 16; ++k){
        u64 e0 = svp[(size_t)i*KK + 2*k];
        u64 e1 = svp[(size_t)i*KK + 2*k + 1];
        cV[2*k]   = u2f((u32)e0);
        cV[2*k+1] = u2f((u32)e1);
        cPp[k] = ((u32)(e0 >> 32) & 0xFFFFu) | (((u32)(e1 >> 32) & 0xFFFFu) << 16);
    }

    // ---- step 0 closed form: fv init = [0, NEG...]; col0 of trans = NEG ----
    float v1 = fmaxf(NEGV, NEGV + cV[0]) + feats[i];
    fvb[1][i] = v1;
    float wm = v1;
#pragma unroll
    for (int o = 32; o > 0; o >>= 1) wm = fmaxf(wm, __shfl_xor(wm, o, 64));
    if (lane == 0) wmaxS[1][wv] = wm;
    __syncthreads();
    float fvmax = wmaxS[1][0];
#pragma unroll
    for (int w = 1; w < 8; ++w) fvmax = fmaxf(fvmax, wmaxS[1][w]);
    {
        u64 q0 = __ballot(v1 > fvmax - 0.5f);
        u64 q1 = __ballot(v1 > fvmax - 1.0f);
        u64 q2 = __ballot(v1 > fvmax - 2.0f);
        u64 q3 = __ballot(v1 > fvmax - 4.0f);
        if (lane == 0){
            bmS[1][0][wv] = q0;
            bmS[1][1][wv] = q1 & ~q0;
            bmS[1][2][wv] = q2 & ~q1;
            bmS[1][3][wv] = q3 & ~q2;
        }
    }
    __syncthreads();

    float featCur = feats[(size_t)1*KK + i];
    int   pPrev = 0; float vPrev = NEGV;   // warm-start: trans[i][0] == NEG exactly

#define TAKE(p_, val_, vv_) { float _val=(val_); int _p=(p_); \
    bool _tk = (_val > best) || (_val == best && _p < barg); \
    best = _tk ? _val : best; barg = _tk ? _p : barg; bvv = _tk ? (vv_) : bvv; }

#define RP(k) ((int)((cPp[(k)>>1] >> (((k)&1)*16)) & 0xFFFFu))
#define REG4(k0) if (!done){ \
    int q0=RP(k0), q1=RP((k0)+1), q2=RP((k0)+2), q3=RP((k0)+3); \
    float f0=fvc[q0], f1=fvc[q1], f2=fvc[q2], f3=fvc[q3]; \
    TAKE(q0, f0+cV[k0],     cV[k0]); \
    TAKE(q1, f1+cV[(k0)+1], cV[(k0)+1]); \
    TAKE(q2, f2+cV[(k0)+2], cV[(k0)+2]); \
    TAKE(q3, f3+cV[(k0)+3], cV[(k0)+3]); }

    for (int t = 1; t < TT; ++t){
        const int cur = t & 1, nxt = cur ^ 1;
        const float* fvc = fvb[cur];
        float featNxt = __builtin_nontemporal_load(
            &feats[(size_t)(t+1 < TT ? t+1 : t)*KK + i]);

        float best; int barg; float bvv;
        if (i == 1){
            // row 1 all NEG: max_p fl(fv[p]+NEG) == fl(fvmax+NEG); bp never on path
            best = fvmax + NEGV; barg = 0; bvv = NEGV;
        } else {
            const float B0f = fvmax - 0.5f;
            const float B1f = fvmax - 1.0f;
            const float B2f = fvmax - 2.0f;
            const float B3f = fvmax - 4.0f;

            // warm start with last step's winner (exact candidate re-eval)
            best = fvc[pPrev] + vPrev; barg = pPrev; bvv = vPrev;
            bool done = false;

            // band walker: batches of 4 with prefetched loads + mid-band bound
            auto evalBand = [&](int b, float Bprev, float vk){
                if (done) return;
                int w = 0;
                u64 m = bmS[cur][b][0];
                for (;;){
                    int q0=0,q1=0,q2=0,q3=0; int cnt = 0;
                    while (cnt < 4 && w < 8){
                        if (m == 0ull){ ++w; m = (w < 8) ? bmS[cur][b][w] : 0ull; continue; }
                        int bit = __builtin_ctzll(m); m &= m - 1;
                        int p = (w << 6) + bit;
                        if      (cnt == 0) q0 = p;
                        else if (cnt == 1) q1 = p;
                        else if (cnt == 2) q2 = p;
                        else               q3 = p;
                        ++cnt;
                    }
                    if (cnt == 0) break;
                    float t0, t1=0, t2=0, t3=0, f0, f1=0, f2=0, f3=0;
                    t0 = transT[(size_t)q0*KK + i];
                    if (cnt > 1) t1 = transT[(size_t)q1*KK + i];
                    if (cnt > 2) t2 = transT[(size_t)q2*KK + i];
                    if (cnt > 3) t3 = transT[(size_t)q3*KK + i];
                    f0 = fvc[q0];
                    if (cnt > 1) f1 = fvc[q1];
                    if (cnt > 2) f2 = fvc[q2];
                    if (cnt > 3) f3 = fvc[q3];
                    TAKE(q0, f0+t0, t0);
                    if (cnt > 1) TAKE(q1, f1+t1, t1);
                    if (cnt > 2) TAKE(q2, f2+t2, t2);
                    if (cnt > 3) TAKE(q3, f3+t3, t3);
                    if (cnt < 4) break;                       // band exhausted
                    if (Bprev + vk < best){ done = true; break; }  // mid-band bound
                }
            };

            REG4(0) REG4(4) REG4(8) REG4(12)
            if (!done) done = (fvmax + cV[15] < best);
            evalBand(0, fvmax, cV[15]);
            if (!done) done = (B0f + cV[15] < best);
            REG4(16) REG4(20) REG4(24) REG4(28)
            if (!done) done = (B0f + cV[31] < best);
            evalBand(1, B0f, cV[31]);
            if (!done) done = (B1f + cV[31] < best);
            evalBand(2, B1f, cV[31]);
            if (!done) done = (B2f + cV[31] < best);
            evalBand(3, B2f, cV[31]);
            if (!done) done = (B3f + cV[31] < best);

            // rare continuation: stream own sorted row from global, bound B3
            int kc = 32;
            while (!done && kc < KK){
#pragma unroll
                for (int j = 0; j < 8; ++j){
                    u64 e = svp[(size_t)i*KK + kc + j];
                    float vv2 = u2f((u32)e); int pp = (int)(e >> 32);
                    TAKE(pp, fvc[pp] + vv2, vv2);
                    if (j == 7) done = (B3f + vv2 < best);
                }
                kc += 8;
            }
        }

        float fvnew = best + featCur;
        __builtin_nontemporal_store((u16)barg, &bp[(size_t)t*KK + i]);
        fvb[nxt][i] = fvnew;
        pPrev = barg; vPrev = bvv;

        float wm2 = fvnew;
#pragma unroll
        for (int o = 32; o > 0; o >>= 1) wm2 = fmaxf(wm2, __shfl_xor(wm2, o, 64));
        if (lane == 0) wmaxS[nxt][wv] = wm2;
        __syncthreads();                       // A: fv/wmax visible
        float fm = wmaxS[nxt][0];
#pragma unroll
        for (int w = 1; w < 8; ++w) fm = fmaxf(fm, wmaxS[nxt][w]);
        {
            u64 q0 = __ballot(fvnew > fm - 0.5f);
            u64 q1 = __ballot(fvnew > fm - 1.0f);
            u64 q2 = __ballot(fvnew > fm - 2.0f);
            u64 q3 = __ballot(fvnew > fm - 4.0f);
            if (lane == 0){
                bmS[nxt][0][wv] = q0;
                bmS[nxt][1][wv] = q1 & ~q0;
                bmS[nxt][2][wv] = q2 & ~q1;
                bmS[nxt][3][wv] = q3 & ~q2;
            }
        }
        fvmax = fm;
        featCur = featNxt;
        __syncthreads();                       // B: band masks visible
    }
#undef REG4
#undef RP
#undef TAKE

    // ---- terminal: terminal[p] = fl(fv_T[p] + NEG); first-index argmax ----
    float tv = fvb[0][i] + NEGV;
    rv[i] = tv; ri[i] = i;
    __syncthreads();
    for (int s2 = 256; s2 > 0; s2 >>= 1){
        if (i < s2){
            float v2 = rv[i+s2]; int i2 = ri[i+s2];
            if (v2 > rv[i] || (v2 == rv[i] && i2 < ri[i])){ rv[i] = v2; ri[i] = i2; }
        }
        __syncthreads();
    }
    if (i == 0){ outScore[0] = rv[0]; *bestOut = ri[0]; }
}

// ---------------------------------------------------------------------------
// Backtrack: segment maps (parallel) -> boundary tags -> per-segment decode.
// ---------------------------------------------------------------------------
__global__ __launch_bounds__(512)
void bt_maps(const u16* __restrict__ bp, u16* __restrict__ maps)
{
    const int s = blockIdx.x, e = threadIdx.x;
    const int tEnd = (s == NSEG-1) ? (TT-1) : (s+1)*SEG;
    const int tLow = s*SEG;
    int cur = e;
    for (int t = tEnd; t > tLow; --t) cur = (int)bp[(size_t)t*KK + cur];
    maps[s*KK + e] = (u16)cur;
}

__global__ void bt_boundaries(const u16* __restrict__ maps, const int* __restrict__ bestP,
                              int* __restrict__ btag)
{
    if (threadIdx.x != 0 || blockIdx.x != 0) return;
    int cur = *bestP;
    for (int s = NSEG-1; s >= 0; --s){
        cur = (int)maps[s*KK + cur];
        btag[s] = cur;
    }
}

__global__ void bt_decode(const u16* __restrict__ bp, const int* __restrict__ btag,
                          const int* __restrict__ bestP, float* __restrict__ outPath)
{
    const int s = blockIdx.x;
    if (threadIdx.x != 0) return;
    int tEnd, cur;
    if (s == NSEG-1){ tEnd = TT-1; cur = *bestP; outPath[TT-1] = (float)cur; }
    else            { tEnd = (s+1)*SEG; cur = btag[s+1]; }
    for (int t = tEnd; t > s*SEG; --t){
        cur = (int)bp[(size_t)t*KK + cur];
        outPath[t-1] = (float)cur;
    }
}

// ---------------------------------------------------------------------------
extern "C" void kernel_launch(void* const* d_in, const int* in_sizes, int n_in,
                              void* d_out, int out_size, void* d_ws, size_t ws_size,
                              hipStream_t stream)
{
    (void)in_sizes; (void)n_in; (void)out_size; (void)ws_size;
    const float* feats = (const float*)d_in[0];
    const float* trans = (const float*)d_in[1];
    float* out = (float*)d_out;

    char* ws = (char*)d_ws;
    size_t off = 0;
    u16*   bp    = (u16*)(ws + off);   off += (size_t)TT*KK*sizeof(u16);   // 64 MB
    u64*   svp   = (u64*)(ws + off);   off += (size_t)KK*KK*sizeof(u64);   // 2 MB
    float* transT= (float*)(ws + off); off += (size_t)KK*KK*sizeof(float); // 1 MB
    u16*   maps  = (u16*)(ws + off);   off += (size_t)NSEG*KK*sizeof(u16); // 256 KB
    int*   btag  = (int*)(ws + off);   off += (size_t)(NSEG+8)*sizeof(int);
    int*   bestP = (int*)(ws + off);

    hipLaunchKernelGGL(sort_rows,     dim3(KK),   dim3(512), 0, stream, trans, svp);
    hipLaunchKernelGGL(transpose_k,   dim3(KK),   dim3(512), 0, stream, trans, transT);
    hipLaunchKernelGGL(viterbi_scan,  dim3(1),    dim3(512), 0, stream, feats, svp, transT, bp, out, bestP);
    hipLaunchKernelGGL(bt_maps,       dim3(NSEG), dim3(512), 0, stream, bp, maps);
    hipLaunchKernelGGL(bt_boundaries, dim3(1),    dim3(64),  0, stream, maps, bestP, btag);
    hipLaunchKernelGGL(bt_decode,     dim3(NSEG), dim3(64),  0, stream, bp, btag, bestP, out + 1);
}

// Round 4
// 729825.488 us; speedup vs baseline: 1.9408x; 1.9408x over previous
//
#include <hip/hip_runtime.h>
#include <cstdint>
#include <cstddef>

#define TT 65536
#define KK 512
#define NEGV (-10000.0f)
#define EDGE 2.0f
#define SEG 256
#define NSEG 256  // TT/SEG

typedef unsigned short u16;
typedef unsigned int   u32;
typedef unsigned long long u64;

__device__ __forceinline__ float u2f(u32 b){ union{u32 u; float f;} x; x.u=b; return x.f; }
__device__ __forceinline__ u32 f2u(float f){ union{u32 u; float f;} x; x.f=f; return x.u; }

// ---------------------------------------------------------------------------
// Per-row sort of transitions, desc by value, asc index on ties.
// TRANSPOSED output: svpT[k*KK + n] = ((u64)p << 32) | float_bits(v) = k-th
// best candidate of row n  (coalesced when all rows read rank k together).
// ---------------------------------------------------------------------------
__global__ __launch_bounds__(512)
void sort_rows(const float* __restrict__ trans, u64* __restrict__ svpT)
{
    __shared__ u64 s[KK];
    const int n = blockIdx.x, i = threadIdx.x;
    float x = trans[n*KK + i];
    u32 b = f2u(x);
    u32 ord = (b & 0x80000000u) ? ~b : (b | 0x80000000u);   // monotone u32 order
    s[i] = ((u64)(~ord) << 16) | (u32)i;                    // asc sort => value desc, p asc
    __syncthreads();
    for (int k = 2; k <= KK; k <<= 1){
        for (int j = k >> 1; j > 0; j >>= 1){
            int ixj = i ^ j;
            if (ixj > i){
                u64 a = s[i], c = s[ixj];
                bool up = ((i & k) == 0);
                if ((a > c) == up){ s[i] = c; s[ixj] = a; }
            }
            __syncthreads();
        }
    }
    u64 key = s[i];
    u32 p    = (u32)(key & 0xFFFFu);
    u32 ordv = ~(u32)(key >> 16);
    u32 bits = (ordv & 0x80000000u) ? (ordv ^ 0x80000000u) : ~ordv;
    svpT[(size_t)i*KK + n] = ((u64)p << 32) | bits;   // rank-major (transposed)
}

// transT[p*KK + n] = trans[n*KK + p]  (gather trans[n,p] lane-coalesced in n)
__global__ __launch_bounds__(512)
void transpose_k(const float* __restrict__ t, float* __restrict__ tt)
{
    const int c = blockIdx.x, r = threadIdx.x;
    tt[(size_t)c*KK + r] = t[(size_t)r*KK + c];
}

// ---------------------------------------------------------------------------
// Main scan: 1 block, 512 threads. Thread i owns row (next-tag) i.
// Exact pruning:
//   evaluated = {p : fv[p] > fvmax-EDGE}  (band, wave-uniform, batched 8-wide)
//            ∪ {top-k of row i by v}      (register list, batched 8-wide)
//   remaining p have fv <= fvmax-EDGE AND v <= cV[k-1]
//   => val <= fl((fvmax-EDGE)+cV[k-1]) < best  terminates (strict: ties safe).
// All straight-line inside batches; branches only on mask/ballot state.
// ---------------------------------------------------------------------------
__global__ __launch_bounds__(512, 2)
void viterbi_scan(const float* __restrict__ feats,
                  const u64* __restrict__ svpT,
                  const float* __restrict__ transT,
                  u16* __restrict__ bp,
                  float* __restrict__ outScore, int* __restrict__ bestOut)
{
    __shared__ float fvb[2][KK];
    __shared__ float wmaxS[2][8];
    __shared__ u64  bmS[2][8];
    __shared__ float rv[KK];
    __shared__ int   ri[KK];

    const int i = threadIdx.x;
    const int lane = i & 63, wv = i >> 6;

    // top-64 (v,p) candidates for own row, v desc (coalesced rank-major loads)
    float cV[64]; u32 cPp[32];
#pragma unroll
    for (int k = 0; k < 32; ++k){
        u64 e0 = svpT[(size_t)(2*k)*KK + i];
        u64 e1 = svpT[(size_t)(2*k+1)*KK + i];
        cV[2*k]   = u2f((u32)e0);
        cV[2*k+1] = u2f((u32)e1);
        cPp[k] = ((u32)(e0 >> 32) & 0xFFFFu) | (((u32)(e1 >> 32) & 0xFFFFu) << 16);
    }

    // ---- step 0 closed form: fv init = [0, NEG...]; col0 of trans = NEG ----
    float v1 = fmaxf(NEGV, NEGV + cV[0]) + feats[i];
    fvb[1][i] = v1;
    float wm = v1;
#pragma unroll
    for (int o = 32; o > 0; o >>= 1) wm = fmaxf(wm, __shfl_xor(wm, o, 64));
    if (lane == 0) wmaxS[1][wv] = wm;
    __syncthreads();
    float fvmax = wmaxS[1][0];
#pragma unroll
    for (int w = 1; w < 8; ++w) fvmax = fmaxf(fvmax, wmaxS[1][w]);
    {
        u64 q = __ballot(v1 > fvmax - EDGE);
        if (lane == 0) bmS[1][wv] = q;
    }
    __syncthreads();

    float featCur = feats[(size_t)1*KK + i];
    int   pPrev = 0; float vPrev = NEGV;   // trans[i][0] == NEG exactly

#define TAKE(p_, val_, vv_) { float _val=(val_); int _p=(p_); \
    bool _tk = (_val > best) || (_val == best && _p < barg); \
    best = _tk ? _val : best; barg = _tk ? _p : barg; bvv = _tk ? (vv_) : bvv; }

#define RP(k) ((int)((cPp[(k)>>1] >> (((k)&1)*16)) & 0xFFFFu))
#define REG8(k0) { \
    int q0=RP(k0),q1=RP((k0)+1),q2=RP((k0)+2),q3=RP((k0)+3); \
    int q4=RP((k0)+4),q5=RP((k0)+5),q6=RP((k0)+6),q7=RP((k0)+7); \
    float f0=fvc[q0],f1=fvc[q1],f2=fvc[q2],f3=fvc[q3]; \
    float f4=fvc[q4],f5=fvc[q5],f6=fvc[q6],f7=fvc[q7]; \
    TAKE(q0,f0+cV[k0],cV[k0]);       TAKE(q1,f1+cV[(k0)+1],cV[(k0)+1]); \
    TAKE(q2,f2+cV[(k0)+2],cV[(k0)+2]); TAKE(q3,f3+cV[(k0)+3],cV[(k0)+3]); \
    TAKE(q4,f4+cV[(k0)+4],cV[(k0)+4]); TAKE(q5,f5+cV[(k0)+5],cV[(k0)+5]); \
    TAKE(q6,f6+cV[(k0)+6],cV[(k0)+6]); TAKE(q7,f7+cV[(k0)+7],cV[(k0)+7]); }

#define RFL(x32) __builtin_amdgcn_readfirstlane((u32)(x32))
#define RFL64(dst, src) { u64 _t = (src); \
    dst = ((u64)RFL((u32)(_t >> 32)) << 32) | (u64)RFL((u32)_t); }

    for (int t = 1; t < TT; ++t){
        const int cur = t & 1, nxt = cur ^ 1;
        const float* fvc = fvb[cur];
        float featNxt = __builtin_nontemporal_load(
            &feats[(size_t)(t+1 < TT ? t+1 : t)*KK + i]);

        float best; int barg; float bvv;
        if (i == 1){
            // row 1 all NEG: max_p fl(fv[p]+NEG) == fl(fvmax+NEG); bp never on path
            best = fvmax + NEGV; barg = 0; bvv = NEGV;
        } else {
            const float Bedge = fvmax - EDGE;
            best = fvc[pPrev] + vPrev; barg = pPrev; bvv = vPrev;   // warm start

            REG8(0) REG8(8)

            // ---- band: wave-uniform scalar stream, batches of 8, no data-dep branches
            {
                u64 M0,M1,M2,M3,M4,M5,M6,M7;
                RFL64(M0, bmS[cur][0]); RFL64(M1, bmS[cur][1]);
                RFL64(M2, bmS[cur][2]); RFL64(M3, bmS[cur][3]);
                RFL64(M4, bmS[cur][4]); RFL64(M5, bmS[cur][5]);
                RFL64(M6, bmS[cur][6]); RFL64(M7, bmS[cur][7]);
                int w = 0; u64 m = M0;
                auto adv = [&](){
                    while (m == 0ull && w < 7){
                        ++w;
                        m = (w==1)?M1:(w==2)?M2:(w==3)?M3:(w==4)?M4:
                            (w==5)?M5:(w==6)?M6:M7;
                    }
                };
                auto nextp = [&](int pad)->int{
                    if (m == 0ull) return pad;
                    int r = (w << 6) + (int)__builtin_ctzll(m);
                    m &= m - 1; adv();
                    return r;
                };
                adv();
                while (m != 0ull){
                    int p0 = nextp(0);
                    int p1 = nextp(p0), p2 = nextp(p0), p3 = nextp(p0);
                    int p4 = nextp(p0), p5 = nextp(p0), p6 = nextp(p0), p7 = nextp(p0);
                    float t0 = transT[(size_t)p0*KK + i], t1 = transT[(size_t)p1*KK + i];
                    float t2 = transT[(size_t)p2*KK + i], t3 = transT[(size_t)p3*KK + i];
                    float t4 = transT[(size_t)p4*KK + i], t5 = transT[(size_t)p5*KK + i];
                    float t6 = transT[(size_t)p6*KK + i], t7 = transT[(size_t)p7*KK + i];
                    float f0 = fvc[p0], f1 = fvc[p1], f2 = fvc[p2], f3 = fvc[p3];
                    float f4 = fvc[p4], f5 = fvc[p5], f6 = fvc[p6], f7 = fvc[p7];
                    TAKE(p0, f0+t0, t0); TAKE(p1, f1+t1, t1);
                    TAKE(p2, f2+t2, t2); TAKE(p3, f3+t3, t3);
                    TAKE(p4, f4+t4, t4); TAKE(p5, f5+t5, t5);
                    TAKE(p6, f6+t6, t6); TAKE(p7, f7+t7, t7);
                }
            }

            bool done = (Bedge + cV[15] < best);
            if (!__all(done)){
                if (!done){ REG8(16) REG8(24) done = (Bedge + cV[31] < best); }
                if (!__all(done)){
                    if (!done){ REG8(32) REG8(40) done = (Bedge + cV[47] < best); }
                    if (!__all(done)){
                        if (!done){ REG8(48) REG8(56) done = (Bedge + cV[63] < best); }
                        // rare: stream deeper ranks (coalesced rank-major)
                        for (int kc = 64; kc < KK && __any(!done); kc += 8){
                            if (!done){
                                float lastv = 0.0f;
#pragma unroll
                                for (int j = 0; j < 8; ++j){
                                    u64 e = svpT[(size_t)(kc+j)*KK + i];
                                    float vv2 = u2f((u32)e); int pp = (int)(e >> 32);
                                    TAKE(pp, fvc[pp] + vv2, vv2);
                                    lastv = vv2;
                                }
                                done = (Bedge + lastv < best);
                            }
                        }
                    }
                }
            }
        }

        float fvnew = best + featCur;
        __builtin_nontemporal_store((u16)barg, &bp[(size_t)t*KK + i]);
        fvb[nxt][i] = fvnew;
        pPrev = barg; vPrev = bvv;

        float wm2 = fvnew;
#pragma unroll
        for (int o = 32; o > 0; o >>= 1) wm2 = fmaxf(wm2, __shfl_xor(wm2, o, 64));
        if (lane == 0) wmaxS[nxt][wv] = wm2;
        __syncthreads();                       // A: fv/wmax visible
        float fm = wmaxS[nxt][0];
#pragma unroll
        for (int w = 1; w < 8; ++w) fm = fmaxf(fm, wmaxS[nxt][w]);
        {
            u64 q = __ballot(fvnew > fm - EDGE);
            if (lane == 0) bmS[nxt][wv] = q;
        }
        fvmax = fm;
        featCur = featNxt;
        __syncthreads();                       // B: band mask visible
    }
#undef REG8
#undef RP
#undef TAKE
#undef RFL
#undef RFL64

    // ---- terminal: terminal[p] = fl(fv_T[p] + NEG); first-index argmax ----
    float tv = fvb[0][i] + NEGV;
    rv[i] = tv; ri[i] = i;
    __syncthreads();
    for (int s2 = 256; s2 > 0; s2 >>= 1){
        if (i < s2){
            float v2 = rv[i+s2]; int i2 = ri[i+s2];
            if (v2 > rv[i] || (v2 == rv[i] && i2 < ri[i])){ rv[i] = v2; ri[i] = i2; }
        }
        __syncthreads();
    }
    if (i == 0){ outScore[0] = rv[0]; *bestOut = ri[0]; }
}

// ---------------------------------------------------------------------------
// Backtrack: segment maps (parallel) -> boundary tags -> per-segment decode.
// ---------------------------------------------------------------------------
__global__ __launch_bounds__(512)
void bt_maps(const u16* __restrict__ bp, u16* __restrict__ maps)
{
    const int s = blockIdx.x, e = threadIdx.x;
    const int tEnd = (s == NSEG-1) ? (TT-1) : (s+1)*SEG;
    const int tLow = s*SEG;
    int cur = e;
    for (int t = tEnd; t > tLow; --t) cur = (int)bp[(size_t)t*KK + cur];
    maps[s*KK + e] = (u16)cur;
}

__global__ void bt_boundaries(const u16* __restrict__ maps, const int* __restrict__ bestP,
                              int* __restrict__ btag)
{
    if (threadIdx.x != 0 || blockIdx.x != 0) return;
    int cur = *bestP;
    for (int s = NSEG-1; s >= 0; --s){
        cur = (int)maps[s*KK + cur];
        btag[s] = cur;
    }
}

__global__ void bt_decode(const u16* __restrict__ bp, const int* __restrict__ btag,
                          const int* __restrict__ bestP, float* __restrict__ outPath)
{
    const int s = blockIdx.x;
    if (threadIdx.x != 0) return;
    int tEnd, cur;
    if (s == NSEG-1){ tEnd = TT-1; cur = *bestP; outPath[TT-1] = (float)cur; }
    else            { tEnd = (s+1)*SEG; cur = btag[s+1]; }
    for (int t = tEnd; t > s*SEG; --t){
        cur = (int)bp[(size_t)t*KK + cur];
        outPath[t-1] = (float)cur;
    }
}

// ---------------------------------------------------------------------------
extern "C" void kernel_launch(void* const* d_in, const int* in_sizes, int n_in,
                              void* d_out, int out_size, void* d_ws, size_t ws_size,
                              hipStream_t stream)
{
    (void)in_sizes; (void)n_in; (void)out_size; (void)ws_size;
    const float* feats = (const float*)d_in[0];
    const float* trans = (const float*)d_in[1];
    float* out = (float*)d_out;

    char* ws = (char*)d_ws;
    size_t off = 0;
    u16*   bp    = (u16*)(ws + off);   off += (size_t)TT*KK*sizeof(u16);   // 64 MB
    u64*   svpT  = (u64*)(ws + off);   off += (size_t)KK*KK*sizeof(u64);   // 2 MB
    float* transT= (float*)(ws + off); off += (size_t)KK*KK*sizeof(float); // 1 MB
    u16*   maps  = (u16*)(ws + off);   off += (size_t)NSEG*KK*sizeof(u16); // 256 KB
    int*   btag  = (int*)(ws + off);   off += (size_t)(NSEG+8)*sizeof(int);
    int*   bestP = (int*)(ws + off);

    hipLaunchKernelGGL(sort_rows,     dim3(KK),   dim3(512), 0, stream, trans, svpT);
    hipLaunchKernelGGL(transpose_k,   dim3(KK),   dim3(512), 0, stream, trans, transT);
    hipLaunchKernelGGL(viterbi_scan,  dim3(1),    dim3(512), 0, stream, feats, svpT, transT, bp, out, bestP);
    hipLaunchKernelGGL(bt_maps,       dim3(NSEG), dim3(512), 0, stream, bp, maps);
    hipLaunchKernelGGL(bt_boundaries, dim3(1),    dim3(64),  0, stream, maps, bestP, btag);
    hipLaunchKernelGGL(bt_decode,     dim3(NSEG), dim3(64),  0, stream, bp, btag, bestP, out + 1);
}

// Round 5
// 546801.416 us; speedup vs baseline: 2.5904x; 1.3347x over previous
//
#include <hip/hip_runtime.h>
#include <cstdint>
#include <cstddef>

#define TT 65536
#define KK 512
#define NEGV (-10000.0f)
#define SEG 256
#define NSEG 256  // TT/SEG

typedef unsigned short u16;
typedef unsigned int   u32;
typedef unsigned long long u64;

__device__ __forceinline__ float u2f(u32 b){ union{u32 u; float f;} x; x.u=b; return x.f; }
__device__ __forceinline__ u32 f2u(float f){ union{u32 u; float f;} x; x.f=f; return x.u; }

// ---------------------------------------------------------------------------
// Per-row sort of transitions, desc by value, asc index on ties.
// TRANSPOSED (rank-major) output: svpT[k*KK + n] = ((u64)p << 32) | bits(v)
// = k-th best candidate of row n (coalesced when all rows read rank k).
// ---------------------------------------------------------------------------
__global__ __launch_bounds__(512)
void sort_rows(const float* __restrict__ trans, u64* __restrict__ svpT)
{
    __shared__ u64 s[KK];
    const int n = blockIdx.x, i = threadIdx.x;
    float x = trans[n*KK + i];
    u32 b = f2u(x);
    u32 ord = (b & 0x80000000u) ? ~b : (b | 0x80000000u);   // monotone u32 order
    s[i] = ((u64)(~ord) << 16) | (u32)i;                    // asc sort => value desc, p asc
    __syncthreads();
    for (int k = 2; k <= KK; k <<= 1){
        for (int j = k >> 1; j > 0; j >>= 1){
            int ixj = i ^ j;
            if (ixj > i){
                u64 a = s[i], c = s[ixj];
                bool up = ((i & k) == 0);
                if ((a > c) == up){ s[i] = c; s[ixj] = a; }
            }
            __syncthreads();
        }
    }
    u64 key = s[i];
    u32 p    = (u32)(key & 0xFFFFu);
    u32 ordv = ~(u32)(key >> 16);
    u32 bits = (ordv & 0x80000000u) ? (ordv ^ 0x80000000u) : ~ordv;
    svpT[(size_t)i*KK + n] = ((u64)p << 32) | bits;   // rank-major
}

// transT[p*KK + n] = trans[n*KK + p]  (gather trans[n,p] lane-coalesced in n)
__global__ __launch_bounds__(512)
void transpose_k(const float* __restrict__ t, float* __restrict__ tt)
{
    const int c = blockIdx.x, r = threadIdx.x;
    tt[(size_t)c*KK + r] = t[(size_t)r*KK + c];
}

// ---------------------------------------------------------------------------
// Main scan: 1 block, 512 threads. Thread i owns row (next-tag) i.
// Per step:
//   publish fv -> wave+block max fm -> 4 fv-band ballots (edges fm-{.5,1,1.5,2})
//   -> LDS compaction into dense ordered list bandE[(fv,p)] (band-major)
//   -> eval: warm start + top-16 v-sorted register candidates + band batches
//      of 8 (broadcast LDS reads + coalesced transT loads), exact joint bound
//      fl(edge_b + cV[15]) < best at band boundaries (strict <: ties never
//      skipped; 3-way compare = numpy first-index argmax). Rare tail streams
//      rank-major svpT with bound fl(e3 + v_last) < best.
// Row 1 (all-NEG transitions) needs no special case: its candidates all carry
// v = NEG, so band 0 yields exactly fl(fm + NEG) and the band-0 bound
// fl((fm-0.5)+NEG) < fl(fm+NEG) terminates it immediately.
// ---------------------------------------------------------------------------
__global__ __launch_bounds__(512)
void viterbi_scan(const float* __restrict__ feats,
                  const u64* __restrict__ svpT,
                  const float* __restrict__ transT,
                  u16* __restrict__ bp,
                  float* __restrict__ outScore, int* __restrict__ bestOut)
{
    __shared__ float fvb[2][KK];
    __shared__ float wmaxS[2][8];
    __shared__ u64  bmS[4][8];
    __shared__ u32  cntS[4][8];
    __shared__ u64  bandE[KK + 8];
    __shared__ float rv[KK];
    __shared__ int   ri[KK];

    const int i = threadIdx.x, lane = i & 63, wv = i >> 6;
    const u64 laneLT = (1ull << lane) - 1ull;

    // top-16 (v,p) of own row — genuinely register-resident (32 VGPRs)
    float cV[16]; int cP[16];
#pragma unroll
    for (int k = 0; k < 16; ++k){
        u64 e = svpT[(size_t)k*KK + i];
        cV[k] = u2f((u32)e); cP[k] = (int)(e >> 32);
    }

    // step 0 closed form: fv_init = [0, NEG..]; col 0 of trans == NEG exactly
    float fv_i = fmaxf(NEGV, NEGV + cV[0]) + feats[i];
    float featCur = feats[(size_t)KK + i];
    int pPrev = 0; float vPrev = NEGV;       // trans[i][0] == NEG exactly

#define TAKE(p_, val_) { float _val=(val_); int _p=(p_); \
    bool _tk = (_val > best) || (_val == best && _p < barg); \
    best = _tk ? _val : best; barg = _tk ? _p : barg; }

#define REG8(k0) { \
    float f0=fvc[cP[k0]],   f1=fvc[cP[(k0)+1]], f2=fvc[cP[(k0)+2]], f3=fvc[cP[(k0)+3]]; \
    float f4=fvc[cP[(k0)+4]], f5=fvc[cP[(k0)+5]], f6=fvc[cP[(k0)+6]], f7=fvc[cP[(k0)+7]]; \
    TAKE(cP[k0],    f0+cV[k0]);      TAKE(cP[(k0)+1], f1+cV[(k0)+1]); \
    TAKE(cP[(k0)+2], f2+cV[(k0)+2]); TAKE(cP[(k0)+3], f3+cV[(k0)+3]); \
    TAKE(cP[(k0)+4], f4+cV[(k0)+4]); TAKE(cP[(k0)+5], f5+cV[(k0)+5]); \
    TAKE(cP[(k0)+6], f6+cV[(k0)+6]); TAKE(cP[(k0)+7], f7+cV[(k0)+7]); }

    for (int t = 1; t < TT; ++t){
        const int cur = t & 1;

        // ---------- publish fv ----------
        fvb[cur][i] = fv_i;
        float wm = fv_i;
#pragma unroll
        for (int o = 32; o > 0; o >>= 1) wm = fmaxf(wm, __shfl_xor(wm, o, 64));
        if (lane == 0) wmaxS[cur][wv] = wm;
        __syncthreads();                                     // A
        float fm = wmaxS[cur][0];
#pragma unroll
        for (int w = 1; w < 8; ++w) fm = fmaxf(fm, wmaxS[cur][w]);
        const float e0 = fm-0.5f, e1 = fm-1.0f, e2 = fm-1.5f, e3 = fm-2.0f;
        u64 q0 = __ballot(fv_i > e0), q1 = __ballot(fv_i > e1);
        u64 q2 = __ballot(fv_i > e2), q3 = __ballot(fv_i > e3);
        if (lane == 0){
            u64 b0 = q0, b1 = q1&~q0, b2 = q2&~q1, b3 = q3&~q2;
            bmS[0][wv]=b0; cntS[0][wv]=(u32)__builtin_popcountll(b0);
            bmS[1][wv]=b1; cntS[1][wv]=(u32)__builtin_popcountll(b1);
            bmS[2][wv]=b2; cntS[2][wv]=(u32)__builtin_popcountll(b2);
            bmS[3][wv]=b3; cntS[3][wv]=(u32)__builtin_popcountll(b3);
        }

        // ---------- overlapped: warm start + REG16 (reads post-A fvb) ----------
        const float* fvc = fvb[cur];
        float featNxt = __builtin_nontemporal_load(
            &feats[(size_t)(t+1 < TT ? t+1 : t)*KK + i]);
        float best = fvc[pPrev] + vPrev; int barg = pPrev;
        REG8(0) REG8(8)
        __syncthreads();                                     // B

        // ---------- compaction ----------
        u32 tot0=0, tot1=0, tot2=0, tot3=0;
#pragma unroll
        for (int w = 0; w < 8; ++w){
            tot0 += cntS[0][w]; tot1 += cntS[1][w];
            tot2 += cntS[2][w]; tot3 += cntS[3][w];
        }
        int b_i = (fv_i > e0) ? 0 : (fv_i > e1) ? 1 : (fv_i > e2) ? 2 :
                  (fv_i > e3) ? 3 : 4;
        if (b_i < 4){
            u32 off = (b_i > 0 ? tot0 : 0u) + (b_i > 1 ? tot1 : 0u) +
                      (b_i > 2 ? tot2 : 0u);
#pragma unroll
            for (int w = 0; w < 8; ++w) off += (w < wv) ? cntS[b_i][w] : 0u;
            off += (u32)__builtin_popcountll(bmS[b_i][wv] & laneLT);
            bandE[off] = ((u64)f2u(fv_i) << 32) | (u32)i;
        }
        u32 totAll = tot0 + tot1 + tot2 + tot3;
        if (i < 8) bandE[totAll + i] = ((u64)f2u(-1.0e30f) << 32);
        int s0 = __builtin_amdgcn_readfirstlane((int)tot0);
        int s1 = __builtin_amdgcn_readfirstlane((int)tot1);
        int s2 = __builtin_amdgcn_readfirstlane((int)tot2);
        int s3 = __builtin_amdgcn_readfirstlane((int)tot3);
        __syncthreads();                                     // C

        // ---------- band eval ----------
        bool done = false;
        int base = 0;
#pragma unroll
        for (int b = 0; b < 4; ++b){
            const int  cntb = (b==0)?s0:(b==1)?s1:(b==2)?s2:s3;
            const float edge = (b==0)?e0:(b==1)?e1:(b==2)?e2:e3;
            if (__any(!done)){
                if (!done && cntb > 0){
                    for (int u = 0; u < cntb; u += 8){
                        const int jj = base + u;
                        u64 E0=bandE[jj],   E1=bandE[jj+1], E2=bandE[jj+2], E3=bandE[jj+3];
                        u64 E4=bandE[jj+4], E5=bandE[jj+5], E6=bandE[jj+6], E7=bandE[jj+7];
                        int p0=(int)(E0&0xFFFFu), p1=(int)(E1&0xFFFFu);
                        int p2=(int)(E2&0xFFFFu), p3=(int)(E3&0xFFFFu);
                        int p4=(int)(E4&0xFFFFu), p5=(int)(E5&0xFFFFu);
                        int p6=(int)(E6&0xFFFFu), p7=(int)(E7&0xFFFFu);
                        float t0=transT[(size_t)p0*KK+i], t1=transT[(size_t)p1*KK+i];
                        float t2=transT[(size_t)p2*KK+i], t3=transT[(size_t)p3*KK+i];
                        float t4=transT[(size_t)p4*KK+i], t5=transT[(size_t)p5*KK+i];
                        float t6=transT[(size_t)p6*KK+i], t7=transT[(size_t)p7*KK+i];
                        TAKE(p0, u2f((u32)(E0>>32))+t0); TAKE(p1, u2f((u32)(E1>>32))+t1);
                        TAKE(p2, u2f((u32)(E2>>32))+t2); TAKE(p3, u2f((u32)(E3>>32))+t3);
                        TAKE(p4, u2f((u32)(E4>>32))+t4); TAKE(p5, u2f((u32)(E5>>32))+t5);
                        TAKE(p6, u2f((u32)(E6>>32))+t6); TAKE(p7, u2f((u32)(E7>>32))+t7);
                    }
                }
                done = done || (edge + cV[15] < best);
            }
            base += cntb;
        }

        // ---------- rare deep tail: rank-major stream, exact bound ----------
        int kc = 16;
        while (__any(!done) && kc < KK){
            if (!done){
                float vlast = NEGV;
#pragma unroll
                for (int j2 = 0; j2 < 8; ++j2){
                    u64 e = svpT[(size_t)(kc+j2)*KK + i];
                    float vv = u2f((u32)e); int pp = (int)(e >> 32);
                    TAKE(pp, fvc[pp] + vv);
                    vlast = vv;
                }
                done = (e3 + vlast < best);
            }
            kc += 8;
        }

        // ---------- finish step ----------
        float fvnew = best + featCur;
        __builtin_nontemporal_store((u16)barg, &bp[(size_t)t*KK + i]);
        pPrev = barg;
        vPrev = transT[(size_t)barg*KK + i];   // prefetch next warm start (exact)
        fv_i = fvnew;
        featCur = featNxt;
    }
#undef REG8
#undef TAKE

    // ---- terminal: terminal[p] = fl(fv_T[p] + NEG); first-index argmax ----
    float tv = fv_i + NEGV;
    rv[i] = tv; ri[i] = i;
    __syncthreads();
    for (int s2 = 256; s2 > 0; s2 >>= 1){
        if (i < s2){
            float v2 = rv[i+s2]; int i2 = ri[i+s2];
            if (v2 > rv[i] || (v2 == rv[i] && i2 < ri[i])){ rv[i] = v2; ri[i] = i2; }
        }
        __syncthreads();
    }
    if (i == 0){ outScore[0] = rv[0]; *bestOut = ri[0]; }
}

// ---------------------------------------------------------------------------
// Backtrack: segment maps (parallel) -> boundary tags -> per-segment decode.
// ---------------------------------------------------------------------------
__global__ __launch_bounds__(512)
void bt_maps(const u16* __restrict__ bp, u16* __restrict__ maps)
{
    const int s = blockIdx.x, e = threadIdx.x;
    const int tEnd = (s == NSEG-1) ? (TT-1) : (s+1)*SEG;
    const int tLow = s*SEG;
    int cur = e;
    for (int t = tEnd; t > tLow; --t) cur = (int)bp[(size_t)t*KK + cur];
    maps[s*KK + e] = (u16)cur;
}

__global__ void bt_boundaries(const u16* __restrict__ maps, const int* __restrict__ bestP,
                              int* __restrict__ btag)
{
    if (threadIdx.x != 0 || blockIdx.x != 0) return;
    int cur = *bestP;
    for (int s = NSEG-1; s >= 0; --s){
        cur = (int)maps[s*KK + cur];
        btag[s] = cur;
    }
}

__global__ void bt_decode(const u16* __restrict__ bp, const int* __restrict__ btag,
                          const int* __restrict__ bestP, float* __restrict__ outPath)
{
    const int s = blockIdx.x;
    if (threadIdx.x != 0) return;
    int tEnd, cur;
    if (s == NSEG-1){ tEnd = TT-1; cur = *bestP; outPath[TT-1] = (float)cur; }
    else            { tEnd = (s+1)*SEG; cur = btag[s+1]; }
    for (int t = tEnd; t > s*SEG; --t){
        cur = (int)bp[(size_t)t*KK + cur];
        outPath[t-1] = (float)cur;
    }
}

// ---------------------------------------------------------------------------
extern "C" void kernel_launch(void* const* d_in, const int* in_sizes, int n_in,
                              void* d_out, int out_size, void* d_ws, size_t ws_size,
                              hipStream_t stream)
{
    (void)in_sizes; (void)n_in; (void)out_size; (void)ws_size;
    const float* feats = (const float*)d_in[0];
    const float* trans = (const float*)d_in[1];
    float* out = (float*)d_out;

    char* ws = (char*)d_ws;
    size_t off = 0;
    u16*   bp    = (u16*)(ws + off);   off += (size_t)TT*KK*sizeof(u16);   // 64 MB
    u64*   svpT  = (u64*)(ws + off);   off += (size_t)KK*KK*sizeof(u64);   // 2 MB
    float* transT= (float*)(ws + off); off += (size_t)KK*KK*sizeof(float); // 1 MB
    u16*   maps  = (u16*)(ws + off);   off += (size_t)NSEG*KK*sizeof(u16); // 256 KB
    int*   btag  = (int*)(ws + off);   off += (size_t)(NSEG+8)*sizeof(int);
    int*   bestP = (int*)(ws + off);

    hipLaunchKernelGGL(sort_rows,     dim3(KK),   dim3(512), 0, stream, trans, svpT);
    hipLaunchKernelGGL(transpose_k,   dim3(KK),   dim3(512), 0, stream, trans, transT);
    hipLaunchKernelGGL(viterbi_scan,  dim3(1),    dim3(512), 0, stream, feats, svpT, transT, bp, out, bestP);
    hipLaunchKernelGGL(bt_maps,       dim3(NSEG), dim3(512), 0, stream, bp, maps);
    hipLaunchKernelGGL(bt_boundaries, dim3(1),    dim3(64),  0, stream, maps, bestP, btag);
    hipLaunchKernelGGL(bt_decode,     dim3(NSEG), dim3(64),  0, stream, bp, btag, bestP, out + 1);
}